// Round 3
// baseline (127.324 us; speedup 1.0000x reference)
//
#include <hip/hip_runtime.h>
#include <hip/hip_bf16.h>

#define NB 64          // number of bins
#define NE (NB + 1)    // number of edges
#define R  32          // histogram replication factor (power of 2)

// ---------------------------------------------------------------------------
// Exact searchsorted(side='right')-1 semantics via uniform guess + fixup.
// ep[g] = (e[g], e[g+1]) so the fixup is ONE ds_read_b64, not two b32s.
// Returns -1 for dropped values (out of range, NaN). Rightmost edge -> NB-1.
// Fixup compares against the ACTUAL edge floats -> bit-exact for any sorted
// edges; for linspace edges the while loops run ~0 iterations.
// ---------------------------------------------------------------------------
__device__ __forceinline__ int bin_of_fast(float x, const float2* __restrict__ ep,
                                           float e0, float eN, float invstep) {
    if (!(x >= e0) || !(x <= eN)) return -1;   // drops NaN too
    if (x == eN) return NB - 1;                // rightmost edge belongs to last bin
    int g = (int)((x - e0) * invstep);
    g = min(max(g, 0), NB - 1);
    float2 p = ep[g];
    while (p.x > x) { --g; p = ep[g]; }        // e[0] <= x guarantees stop
    while (p.y <= x) { ++g; p = ep[g]; }       // x < e[NB] guarantees stop
    return g;
}

// ---------------------------------------------------------------------------
// Kernel 1: fused dual masked histogram, 32x replicated LDS histograms.
// Layout [R][NE] (stride 65 words): bank(r,b) = (r + b) % 32. c = tid & 31
// -> only lanes i and i+32 can share an address (2-way max; free per m136).
// counts in ws: [0 .. B*NB) = obs, [B*NB .. 2*B*NB) = pred (uint32)
// ---------------------------------------------------------------------------
__global__ void __launch_bounds__(256)
hist_kernel(const float* __restrict__ obs,
            const float* __restrict__ pred,
            const int*   __restrict__ mask,
            const float* __restrict__ edges,
            unsigned int* __restrict__ counts,
            int elemsPerBatch, int blocksPerBatch, int B)
{
    __shared__ float2       s_epair[NB];
    __shared__ unsigned int s_obs[R][NE];
    __shared__ unsigned int s_pred[R][NE];

    const int tid = threadIdx.x;
    for (int i = tid; i < R * NE; i += blockDim.x) {
        (&s_obs[0][0])[i]  = 0u;
        (&s_pred[0][0])[i] = 0u;
    }
    if (tid < NB) s_epair[tid] = make_float2(edges[tid], edges[tid + 1]);
    __syncthreads();

    const float e0 = edges[0];
    const float eN = edges[NB];
    const float invstep = (float)NB / (eN - e0);

    const int b     = blockIdx.x / blocksPerBatch;
    const int chunk = blockIdx.x % blocksPerBatch;
    const int perBlock = elemsPerBatch / blocksPerBatch;
    const size_t base  = (size_t)b * (size_t)elemsPerBatch;

    const float4* o4 = reinterpret_cast<const float4*>(obs  + base);
    const float4* p4 = reinterpret_cast<const float4*>(pred + base);
    const int4*   m4 = reinterpret_cast<const int4*>(mask + base);

    const int startV = (chunk * perBlock) >> 2;
    const int endV   = startV + (perBlock >> 2);
    const int c = tid & (R - 1);

#define PROC(o, p, m)                                                        \
    do {                                                                     \
        if ((m).x) {                                                         \
            int io = bin_of_fast((o).x, s_epair, e0, eN, invstep);           \
            if (io >= 0) atomicAdd(&s_obs[c][io], 1u);                       \
            int ip = bin_of_fast((p).x, s_epair, e0, eN, invstep);           \
            if (ip >= 0) atomicAdd(&s_pred[c][ip], 1u);                      \
        }                                                                    \
        if ((m).y) {                                                         \
            int io = bin_of_fast((o).y, s_epair, e0, eN, invstep);           \
            if (io >= 0) atomicAdd(&s_obs[c][io], 1u);                       \
            int ip = bin_of_fast((p).y, s_epair, e0, eN, invstep);           \
            if (ip >= 0) atomicAdd(&s_pred[c][ip], 1u);                      \
        }                                                                    \
        if ((m).z) {                                                         \
            int io = bin_of_fast((o).z, s_epair, e0, eN, invstep);           \
            if (io >= 0) atomicAdd(&s_obs[c][io], 1u);                       \
            int ip = bin_of_fast((p).z, s_epair, e0, eN, invstep);           \
            if (ip >= 0) atomicAdd(&s_pred[c][ip], 1u);                      \
        }                                                                    \
        if ((m).w) {                                                         \
            int io = bin_of_fast((o).w, s_epair, e0, eN, invstep);           \
            if (io >= 0) atomicAdd(&s_obs[c][io], 1u);                       \
            int ip = bin_of_fast((p).w, s_epair, e0, eN, invstep);           \
            if (ip >= 0) atomicAdd(&s_pred[c][ip], 1u);                      \
        }                                                                    \
    } while (0)

    // 2x unroll: two independent float4 groups in flight per iteration.
    for (int i = startV + tid; i < endV; i += 2 * (int)blockDim.x) {
        const int j = i + (int)blockDim.x;
        float4 o0 = o4[i];
        float4 q0 = p4[i];
        int4   m0 = m4[i];
        float4 o1, q1;
        int4   m1;
        const bool has2 = (j < endV);
        if (has2) { o1 = o4[j]; q1 = p4[j]; m1 = m4[j]; }
        PROC(o0, q0, m0);
        if (has2) PROC(o1, q1, m1);
    }
#undef PROC
    __syncthreads();

    if (tid < NB) {
        unsigned int so = 0u, sp = 0u;
        #pragma unroll
        for (int r = 0; r < R; ++r) { so += s_obs[r][tid]; sp += s_pred[r][tid]; }
        if (so) atomicAdd(&counts[(size_t)b * NB + tid], so);
        if (sp) atomicAdd(&counts[(size_t)B * NB + (size_t)b * NB + tid], sp);
    }
}

// ---------------------------------------------------------------------------
// Kernel 2: finalize. One wave, lane t = bin t.
// out[0] = w2_loss, out[1 .. 1+B*NB) = p_obs, out[1+B*NB ..) = p_pred
// ---------------------------------------------------------------------------
__device__ __forceinline__ float wave_sum64(float v) {
    for (int o = 32; o > 0; o >>= 1) v += __shfl_xor(v, o, 64);
    return v;
}
__device__ __forceinline__ float wave_incl_scan64(float v, int lane) {
    for (int d = 1; d < 64; d <<= 1) {
        float u = __shfl_up(v, d, 64);
        if (lane >= d) v += u;
    }
    return v;
}

__global__ void __launch_bounds__(64)
finalize_kernel(const unsigned int* __restrict__ counts,
                const float* __restrict__ edges,
                const float* __restrict__ bweights,
                float* __restrict__ out, int B)
{
    const int t = threadIdx.x;    // 0..63 == bin index

    float midA = 0.5f * (edges[t] + edges[t + 1]);
    float width;
    if (t < NB - 1) {
        float midB = 0.5f * (edges[t + 1] + edges[t + 2]);
        width = midB - midA;
    } else {
        float midPrev = 0.5f * (edges[NB - 2] + edges[NB - 1]);
        width = midA - midPrev;
    }
    const float bw = bweights[t];

    float loss_acc = 0.0f;
    for (int b = 0; b < B; ++b) {
        float co = (float)counts[(size_t)b * NB + t];
        float cp = (float)counts[(size_t)B * NB + (size_t)b * NB + t];

        float to = wave_sum64(co);
        if (to == 0.0f) { co = 1.0f; to = 64.0f; }
        float tp = wave_sum64(cp);
        if (tp == 0.0f) { cp = 1.0f; tp = 64.0f; }

        float po = co / to;
        float pp = cp / tp;
        out[1 + (size_t)b * NB + t]                  = po;
        out[1 + (size_t)B * NB + (size_t)b * NB + t] = pp;

        float cdfo = wave_incl_scan64(po, t);
        float cdfp = wave_incl_scan64(pp, t);
        float d = cdfo - cdfp;
        float wd = d * d * width * bw;
        float s = wave_sum64(wd);
        if (t == 0) loss_acc += s;
    }
    if (t == 0) out[0] = loss_acc / (float)B;
}

// ---------------------------------------------------------------------------
extern "C" void kernel_launch(void* const* d_in, const int* in_sizes, int n_in,
                              void* d_out, int out_size, void* d_ws, size_t ws_size,
                              hipStream_t stream) {
    const float* obs      = (const float*)d_in[0];
    const float* pred     = (const float*)d_in[1];
    const int*   mask     = (const int*)d_in[2];
    const float* edges    = (const float*)d_in[3];
    const float* bweights = (const float*)d_in[4];
    float* out = (float*)d_out;

    const int nb = in_sizes[3] - 1;                 // 64
    const int B  = (out_size - 1) / (2 * nb);       // 32
    const int elemsPerBatch = in_sizes[0] / B;      // 1048576

    unsigned int* counts = (unsigned int*)d_ws;     // [2][B][nb] uint32
    const size_t countsBytes = (size_t)2 * B * nb * sizeof(unsigned int);

    hipMemsetAsync(d_ws, 0, countsBytes, stream);

    const int blocksPerBatch = 64;                  // 16384 elems / block
    dim3 grid(B * blocksPerBatch), block(256);
    hist_kernel<<<grid, block, 0, stream>>>(obs, pred, mask, edges, counts,
                                            elemsPerBatch, blocksPerBatch, B);

    finalize_kernel<<<1, 64, 0, stream>>>(counts, edges, bweights, out, B);
}

// Round 4
// 122.392 us; speedup vs baseline: 1.0403x; 1.0403x over previous
//
#include <hip/hip_runtime.h>
#include <hip/hip_bf16.h>

#define NB 64          // number of bins
#define NE (NB + 1)    // number of edges
#define RC 32          // replica columns (one per bank)

// ---------------------------------------------------------------------------
// Histogram LDS layout: s_hist[bin][replica], replica = lane & 31.
// addr = bin*32 + c  ->  bank = c  ->  every wave atomic: 32 banks x 2 lanes,
// data-independent, conflict-free (2-way is free).
// ---------------------------------------------------------------------------

// Register-only exact binning, valid when edges[k] == e0 + k*step bitwise
// (verified once per block). searchsorted(side='right')-1 semantics:
// returns g with recon(g) <= x < recon(g+1); -1 for out-of-range/NaN;
// x == eN -> NB-1.
__device__ __forceinline__ int bin_affine(float x, float e0, float eN,
                                          float step, float invstep) {
    if (!(x >= e0) || !(x <= eN)) return -1;     // drops NaN too
    if (x == eN) return NB - 1;
    int g = (int)((x - e0) * invstep);
    g = min(max(g, 0), NB - 1);
    float lo = e0 + (float)g * step;             // == edges[g] exactly
    while (lo > x) { --g; lo = e0 + (float)g * step; }
    float hi = e0 + (float)(g + 1) * step;       // == edges[g+1] exactly
    while (hi <= x) { ++g; hi = e0 + (float)(g + 1) * step; }
    return g;
}

// Fallback: exact binning against the real edge array (LDS pairs).
__device__ __forceinline__ int bin_lds(float x, const float2* __restrict__ ep,
                                       float e0, float eN, float invstep) {
    if (!(x >= e0) || !(x <= eN)) return -1;
    if (x == eN) return NB - 1;
    int g = (int)((x - e0) * invstep);
    g = min(max(g, 0), NB - 1);
    float2 p = ep[g];
    while (p.x > x) { --g; p = ep[g]; }
    while (p.y <= x) { ++g; p = ep[g]; }
    return g;
}

template <bool AFFINE>
__device__ __forceinline__ void
stream_hist(const float4* __restrict__ o4, const float4* __restrict__ p4,
            const int4* __restrict__ m4, int startV, int endV, int tid,
            unsigned int (*s_obs)[RC], unsigned int (*s_pred)[RC],
            const float2* __restrict__ s_epair,
            float e0, float eN, float step, float invstep)
{
    const int c = tid & (RC - 1);

#define BIN(x) (AFFINE ? bin_affine((x), e0, eN, step, invstep) \
                       : bin_lds((x), s_epair, e0, eN, invstep))
#define PROC(o, p, m)                                              \
    do {                                                           \
        int io, ip;                                                \
        io = BIN((o).x); ip = BIN((p).x);                          \
        if ((m).x && io >= 0) atomicAdd(&s_obs[io][c], 1u);        \
        if ((m).x && ip >= 0) atomicAdd(&s_pred[ip][c], 1u);       \
        io = BIN((o).y); ip = BIN((p).y);                          \
        if ((m).y && io >= 0) atomicAdd(&s_obs[io][c], 1u);        \
        if ((m).y && ip >= 0) atomicAdd(&s_pred[ip][c], 1u);       \
        io = BIN((o).z); ip = BIN((p).z);                          \
        if ((m).z && io >= 0) atomicAdd(&s_obs[io][c], 1u);        \
        if ((m).z && ip >= 0) atomicAdd(&s_pred[ip][c], 1u);       \
        io = BIN((o).w); ip = BIN((p).w);                          \
        if ((m).w && io >= 0) atomicAdd(&s_obs[io][c], 1u);        \
        if ((m).w && ip >= 0) atomicAdd(&s_pred[ip][c], 1u);       \
    } while (0)

    for (int i = startV + tid; i < endV; i += 2 * 256) {
        const int j = i + 256;
        float4 o0 = o4[i];
        float4 q0 = p4[i];
        int4   m0 = m4[i];
        float4 o1, q1;
        int4   m1;
        const bool has2 = (j < endV);
        if (has2) { o1 = o4[j]; q1 = p4[j]; m1 = m4[j]; }
        PROC(o0, q0, m0);
        if (has2) PROC(o1, q1, m1);
    }
#undef PROC
#undef BIN
}

__global__ void __launch_bounds__(256)
hist_kernel(const float* __restrict__ obs,
            const float* __restrict__ pred,
            const int*   __restrict__ mask,
            const float* __restrict__ edges,
            unsigned int* __restrict__ counts,   // [2][B][NB]
            int elemsPerBatch, int blocksPerBatch, int B)
{
    __shared__ unsigned int s_obs[NB][RC];
    __shared__ unsigned int s_pred[NB][RC];
    __shared__ float2       s_epair[NB];
    __shared__ int          s_affine;

    const int tid = threadIdx.x;
    for (int i = tid; i < NB * RC; i += 256) {
        (&s_obs[0][0])[i]  = 0u;
        (&s_pred[0][0])[i] = 0u;
    }
    if (tid < NB) s_epair[tid] = make_float2(edges[tid], edges[tid + 1]);
    if (tid == 0) s_affine = 1;
    __syncthreads();

    const float e0 = edges[0];
    const float eN = edges[NB];
    const float step    = (eN - e0) / (float)NB;
    const float invstep = 1.0f / step;

    // verify the register-reconstruction is bitwise-faithful to the edges
    if (tid < NE) {
        float recon = e0 + (float)tid * step;
        if (!(recon == edges[tid]) || !(step > 0.0f)) atomicAnd(&s_affine, 0);
    }
    __syncthreads();
    const bool affine = (s_affine != 0);

    const int b     = blockIdx.x / blocksPerBatch;
    const int chunk = blockIdx.x % blocksPerBatch;
    const int perBlock = elemsPerBatch / blocksPerBatch;
    const size_t base  = (size_t)b * (size_t)elemsPerBatch;

    const float4* o4 = reinterpret_cast<const float4*>(obs  + base);
    const float4* p4 = reinterpret_cast<const float4*>(pred + base);
    const int4*   m4 = reinterpret_cast<const int4*>(mask + base);

    const int startV = (chunk * perBlock) >> 2;
    const int endV   = startV + (perBlock >> 2);

    if (affine)
        stream_hist<true >(o4, p4, m4, startV, endV, tid, s_obs, s_pred,
                           s_epair, e0, eN, step, invstep);
    else
        stream_hist<false>(o4, p4, m4, startV, endV, tid, s_obs, s_pred,
                           s_epair, e0, eN, step, invstep);

    __syncthreads();

    if (tid < NB) {
        unsigned int so = 0u, sp = 0u;
        #pragma unroll
        for (int r = 0; r < RC; ++r) {
            int col = (tid + r) & (RC - 1);      // rotated -> conflict-free
            so += s_obs[tid][col];
            sp += s_pred[tid][col];
        }
        if (so) atomicAdd(&counts[(size_t)b * NB + tid], so);
        if (sp) atomicAdd(&counts[(size_t)B * NB + (size_t)b * NB + tid], sp);
    }
}

// ---------------------------------------------------------------------------
// Kernel 2: finalize. One wave, lane t = bin t.
// out[0] = w2_loss, out[1 .. 1+B*NB) = p_obs, out[1+B*NB ..) = p_pred
// ---------------------------------------------------------------------------
__device__ __forceinline__ float wave_sum64(float v) {
    for (int o = 32; o > 0; o >>= 1) v += __shfl_xor(v, o, 64);
    return v;
}
__device__ __forceinline__ float wave_incl_scan64(float v, int lane) {
    for (int d = 1; d < 64; d <<= 1) {
        float u = __shfl_up(v, d, 64);
        if (lane >= d) v += u;
    }
    return v;
}

__global__ void __launch_bounds__(64)
finalize_kernel(const unsigned int* __restrict__ counts,
                const float* __restrict__ edges,
                const float* __restrict__ bweights,
                float* __restrict__ out, int B)
{
    const int t = threadIdx.x;    // 0..63 == bin index

    float midA = 0.5f * (edges[t] + edges[t + 1]);
    float width;
    if (t < NB - 1) {
        float midB = 0.5f * (edges[t + 1] + edges[t + 2]);
        width = midB - midA;
    } else {
        float midPrev = 0.5f * (edges[NB - 2] + edges[NB - 1]);
        width = midA - midPrev;
    }
    const float bw = bweights[t];

    float loss_acc = 0.0f;
    for (int b = 0; b < B; ++b) {
        float co = (float)counts[(size_t)b * NB + t];
        float cp = (float)counts[(size_t)B * NB + (size_t)b * NB + t];

        float to = wave_sum64(co);
        if (to == 0.0f) { co = 1.0f; to = 64.0f; }
        float tp = wave_sum64(cp);
        if (tp == 0.0f) { cp = 1.0f; tp = 64.0f; }

        float po = co / to;
        float pp = cp / tp;
        out[1 + (size_t)b * NB + t]                  = po;
        out[1 + (size_t)B * NB + (size_t)b * NB + t] = pp;

        float cdfo = wave_incl_scan64(po, t);
        float cdfp = wave_incl_scan64(pp, t);
        float d = cdfo - cdfp;
        float wd = d * d * width * bw;
        float s = wave_sum64(wd);
        if (t == 0) loss_acc += s;
    }
    if (t == 0) out[0] = loss_acc / (float)B;
}

// ---------------------------------------------------------------------------
extern "C" void kernel_launch(void* const* d_in, const int* in_sizes, int n_in,
                              void* d_out, int out_size, void* d_ws, size_t ws_size,
                              hipStream_t stream) {
    const float* obs      = (const float*)d_in[0];
    const float* pred     = (const float*)d_in[1];
    const int*   mask     = (const int*)d_in[2];
    const float* edges    = (const float*)d_in[3];
    const float* bweights = (const float*)d_in[4];
    float* out = (float*)d_out;

    const int nb = in_sizes[3] - 1;                 // 64
    const int B  = (out_size - 1) / (2 * nb);       // 32
    const int elemsPerBatch = in_sizes[0] / B;      // 1048576

    unsigned int* counts = (unsigned int*)d_ws;     // [2][B][nb] uint32
    const size_t countsBytes = (size_t)2 * B * nb * sizeof(unsigned int);

    hipMemsetAsync(d_ws, 0, countsBytes, stream);

    const int blocksPerBatch = 64;                  // 16384 elems / block
    dim3 grid(B * blocksPerBatch), block(256);
    hist_kernel<<<grid, block, 0, stream>>>(obs, pred, mask, edges, counts,
                                            elemsPerBatch, blocksPerBatch, B);

    finalize_kernel<<<1, 64, 0, stream>>>(counts, edges, bweights, out, B);
}

// Round 5
// 116.765 us; speedup vs baseline: 1.0904x; 1.0482x over previous
//
#include <hip/hip_runtime.h>
#include <hip/hip_bf16.h>

#define NB   64          // number of bins
#define NE   (NB + 1)    // number of edges
#define RC   32          // replica columns (one per bank)
#define ROWS (NB + 1)    // +1 trash row for invalid/masked-out elements

// ---------------------------------------------------------------------------
// Branchless exact binning for affine (linspace) edges, verified bitwise per
// block. Guess g = (int)((x-e0)*invstep) is within 1 bin of truth (f32 error
// < 2^-14 bins for 64 bins), so ONE compare-adjust per direction suffices.
// recon(k) = fma(k, step, e0) == edges[k] bitwise (checked). Returns -1 for
// out-of-range/NaN; x == eN -> NB-1. No branches, no LDS reads.
// ---------------------------------------------------------------------------
__device__ __forceinline__ int bin_affine(float x, float e0, float eN,
                                          float step, float invstep) {
    float t = (x - e0) * invstep;
    int g = (int)t;
    g = min(max(g, 0), NB - 1);
    float lo = fmaf((float)g, step, e0);         // == edges[g] exactly
    float hi = fmaf((float)(g + 1), step, e0);   // == edges[g+1] exactly
    g += (hi <= x) ? 1 : 0;
    g -= (lo > x) ? 1 : 0;
    g = (x == eN) ? (NB - 1) : g;
    bool inr = (x >= e0) && (x <= eN);           // false for NaN
    return inr ? g : -1;
}

// Fallback: exact binning against arbitrary sorted edges (LDS pairs, loops).
__device__ __forceinline__ int bin_lds(float x, const float2* __restrict__ ep,
                                       float e0, float eN, float invstep) {
    if (!(x >= e0) || !(x <= eN)) return -1;
    if (x == eN) return NB - 1;
    int g = (int)((x - e0) * invstep);
    g = min(max(g, 0), NB - 1);
    float2 p = ep[g];
    while (p.x > x) { --g; p = ep[g]; }
    while (p.y <= x) { ++g; p = ep[g]; }
    return g;
}

// ---------------------------------------------------------------------------
// Kernel 1: fused dual masked histogram.
// LDS layout: hist[arr][row][col], addr = ((arr*ROWS+row)<<5) + (lane&31)
// -> bank = lane&31 always: data-independent, conflict-free (2 lanes/bank).
// Invalid elements hit row NB (trash). All atomics unconditional.
// Hot loop: branchless, software-pipelined 2 stages x 2 float4-triples.
// ---------------------------------------------------------------------------
template <bool AFFINE>
__device__ __forceinline__ void
stream_hist(const float4* __restrict__ o4, const float4* __restrict__ p4,
            const int4* __restrict__ m4, int startV, int endV, int tid,
            unsigned int* __restrict__ hobs, unsigned int* __restrict__ hpred,
            const float2* __restrict__ s_epair,
            float e0, float eN, float step, float invstep)
{
#define BIN(x) (AFFINE ? bin_affine((x), e0, eN, step, invstep) \
                       : bin_lds((x), s_epair, e0, eN, invstep))
#define PROC(o, q, m)                                                        \
    do {                                                                     \
        int io0 = BIN((o).x), ip0 = BIN((q).x);                              \
        int io1 = BIN((o).y), ip1 = BIN((q).y);                              \
        int io2 = BIN((o).z), ip2 = BIN((q).z);                              \
        int io3 = BIN((o).w), ip3 = BIN((q).w);                              \
        io0 = ((m).x && io0 >= 0) ? io0 : NB;                                \
        ip0 = ((m).x && ip0 >= 0) ? ip0 : NB;                                \
        io1 = ((m).y && io1 >= 0) ? io1 : NB;                                \
        ip1 = ((m).y && ip1 >= 0) ? ip1 : NB;                                \
        io2 = ((m).z && io2 >= 0) ? io2 : NB;                                \
        ip2 = ((m).z && ip2 >= 0) ? ip2 : NB;                                \
        io3 = ((m).w && io3 >= 0) ? io3 : NB;                                \
        ip3 = ((m).w && ip3 >= 0) ? ip3 : NB;                                \
        atomicAdd(hobs  + (io0 << 5), 1u);                                   \
        atomicAdd(hpred + (ip0 << 5), 1u);                                   \
        atomicAdd(hobs  + (io1 << 5), 1u);                                   \
        atomicAdd(hpred + (ip1 << 5), 1u);                                   \
        atomicAdd(hobs  + (io2 << 5), 1u);                                   \
        atomicAdd(hpred + (ip2 << 5), 1u);                                   \
        atomicAdd(hobs  + (io3 << 5), 1u);                                   \
        atomicAdd(hpred + (ip3 << 5), 1u);                                   \
    } while (0)

    const int nFull = (endV - startV) / 512;   // full 2-triple stages
    int i = startV + tid;

    float4 oA, qA, oB, qB;
    int4   mA, mB;
    if (nFull > 0) {
        oA = o4[i];       qA = p4[i];       mA = m4[i];
        oB = o4[i + 256]; qB = p4[i + 256]; mB = m4[i + 256];
    }
    for (int s = 0; s < nFull; ++s) {
        // prefetch next stage (safe dummy address on last stage)
        const int j = (s + 1 < nFull) ? (i + 512) : (startV + tid);
        float4 oC = o4[j];       float4 qC = p4[j];       int4 mC = m4[j];
        float4 oD = o4[j + 256]; float4 qD = p4[j + 256]; int4 mD = m4[j + 256];
        PROC(oA, qA, mA);
        PROC(oB, qB, mB);
        oA = oC; qA = qC; mA = mC;
        oB = oD; qB = qD; mB = mD;
        i += 512;
    }
    // tail (generic; empty for the benchmark shape)
    for (; i < endV; i += 256) {
        float4 o = o4[i]; float4 q = p4[i]; int4 m = m4[i];
        PROC(o, q, m);
    }
#undef PROC
#undef BIN
}

__global__ void __launch_bounds__(256)
hist_kernel(const float* __restrict__ obs,
            const float* __restrict__ pred,
            const int*   __restrict__ mask,
            const float* __restrict__ edges,
            unsigned int* __restrict__ counts,   // [2][B][NB]
            int elemsPerBatch, int blocksPerBatch, int B)
{
    __shared__ unsigned int s_hist[2][ROWS][RC];
    __shared__ float2       s_epair[NB];
    __shared__ int          s_affine;

    const int tid = threadIdx.x;
    for (int i = tid; i < 2 * ROWS * RC; i += 256)
        (&s_hist[0][0][0])[i] = 0u;
    if (tid < NB) s_epair[tid] = make_float2(edges[tid], edges[tid + 1]);
    if (tid == 0) s_affine = 1;
    __syncthreads();

    const float e0 = edges[0];
    const float eN = edges[NB];
    const float step    = (eN - e0) / (float)NB;
    const float invstep = 1.0f / step;

    // verify register-reconstruction is bitwise-faithful to the edge array
    if (tid < NE) {
        float recon = fmaf((float)tid, step, e0);
        if (!(recon == edges[tid]) || !(step > 0.0f)) atomicAnd(&s_affine, 0);
    }
    __syncthreads();
    const bool affine = (s_affine != 0);

    const int b     = blockIdx.x / blocksPerBatch;
    const int chunk = blockIdx.x % blocksPerBatch;
    const int perBlock = elemsPerBatch / blocksPerBatch;
    const size_t base  = (size_t)b * (size_t)elemsPerBatch;

    const float4* o4 = reinterpret_cast<const float4*>(obs  + base);
    const float4* p4 = reinterpret_cast<const float4*>(pred + base);
    const int4*   m4 = reinterpret_cast<const int4*>(mask + base);

    const int startV = (chunk * perBlock) >> 2;
    const int endV   = startV + (perBlock >> 2);

    const int c = tid & (RC - 1);
    unsigned int* hobs  = &s_hist[0][0][0] + c;
    unsigned int* hpred = &s_hist[1][0][0] + c;

    if (affine)
        stream_hist<true >(o4, p4, m4, startV, endV, tid, hobs, hpred,
                           s_epair, e0, eN, step, invstep);
    else
        stream_hist<false>(o4, p4, m4, startV, endV, tid, hobs, hpred,
                           s_epair, e0, eN, step, invstep);

    __syncthreads();

    if (tid < NB) {
        unsigned int so = 0u, sp = 0u;
        #pragma unroll
        for (int r = 0; r < RC; ++r) {
            int col = (tid + r) & (RC - 1);      // rotated -> conflict-free
            so += s_hist[0][tid][col];
            sp += s_hist[1][tid][col];
        }
        if (so) atomicAdd(&counts[(size_t)b * NB + tid], so);
        if (sp) atomicAdd(&counts[(size_t)B * NB + (size_t)b * NB + tid], sp);
    }
}

// ---------------------------------------------------------------------------
// Kernel 2: finalize. One wave, lane t = bin t.
// out[0] = w2_loss, out[1 .. 1+B*NB) = p_obs, out[1+B*NB ..) = p_pred
// ---------------------------------------------------------------------------
__device__ __forceinline__ float wave_sum64(float v) {
    for (int o = 32; o > 0; o >>= 1) v += __shfl_xor(v, o, 64);
    return v;
}
__device__ __forceinline__ float wave_incl_scan64(float v, int lane) {
    for (int d = 1; d < 64; d <<= 1) {
        float u = __shfl_up(v, d, 64);
        if (lane >= d) v += u;
    }
    return v;
}

__global__ void __launch_bounds__(64)
finalize_kernel(const unsigned int* __restrict__ counts,
                const float* __restrict__ edges,
                const float* __restrict__ bweights,
                float* __restrict__ out, int B)
{
    const int t = threadIdx.x;    // 0..63 == bin index

    float midA = 0.5f * (edges[t] + edges[t + 1]);
    float width;
    if (t < NB - 1) {
        float midB = 0.5f * (edges[t + 1] + edges[t + 2]);
        width = midB - midA;
    } else {
        float midPrev = 0.5f * (edges[NB - 2] + edges[NB - 1]);
        width = midA - midPrev;
    }
    const float bw = bweights[t];

    float loss_acc = 0.0f;
    for (int b = 0; b < B; ++b) {
        float co = (float)counts[(size_t)b * NB + t];
        float cp = (float)counts[(size_t)B * NB + (size_t)b * NB + t];

        float to = wave_sum64(co);
        if (to == 0.0f) { co = 1.0f; to = 64.0f; }
        float tp = wave_sum64(cp);
        if (tp == 0.0f) { cp = 1.0f; tp = 64.0f; }

        float po = co / to;
        float pp = cp / tp;
        out[1 + (size_t)b * NB + t]                  = po;
        out[1 + (size_t)B * NB + (size_t)b * NB + t] = pp;

        float cdfo = wave_incl_scan64(po, t);
        float cdfp = wave_incl_scan64(pp, t);
        float d = cdfo - cdfp;
        float wd = d * d * width * bw;
        float s = wave_sum64(wd);
        if (t == 0) loss_acc += s;
    }
    if (t == 0) out[0] = loss_acc / (float)B;
}

// ---------------------------------------------------------------------------
extern "C" void kernel_launch(void* const* d_in, const int* in_sizes, int n_in,
                              void* d_out, int out_size, void* d_ws, size_t ws_size,
                              hipStream_t stream) {
    const float* obs      = (const float*)d_in[0];
    const float* pred     = (const float*)d_in[1];
    const int*   mask     = (const int*)d_in[2];
    const float* edges    = (const float*)d_in[3];
    const float* bweights = (const float*)d_in[4];
    float* out = (float*)d_out;

    const int nb = in_sizes[3] - 1;                 // 64
    const int B  = (out_size - 1) / (2 * nb);       // 32
    const int elemsPerBatch = in_sizes[0] / B;      // 1048576

    unsigned int* counts = (unsigned int*)d_ws;     // [2][B][nb] uint32
    const size_t countsBytes = (size_t)2 * B * nb * sizeof(unsigned int);

    hipMemsetAsync(d_ws, 0, countsBytes, stream);

    const int blocksPerBatch = 64;                  // 16384 elems / block
    dim3 grid(B * blocksPerBatch), block(256);
    hist_kernel<<<grid, block, 0, stream>>>(obs, pred, mask, edges, counts,
                                            elemsPerBatch, blocksPerBatch, B);

    finalize_kernel<<<1, 64, 0, stream>>>(counts, edges, bweights, out, B);
}

// Round 6
// 111.265 us; speedup vs baseline: 1.1443x; 1.0494x over previous
//
#include <hip/hip_runtime.h>
#include <hip/hip_bf16.h>

#define NB   64          // number of bins
#define NE   (NB + 1)    // number of edges
#define RC   32          // replica columns (one per bank)
#define ROWS (NB + 1)    // +1 trash row for invalid/masked-out elements

// ---------------------------------------------------------------------------
// Branchless exact binning for affine (linspace) edges, verified bitwise per
// block. Guess g = (int)((x-e0)*invstep) is within 1 bin of truth, so one
// compare-adjust per direction suffices. recon(k) = fma(k,step,e0) ==
// edges[k] bitwise (checked once per block). x == eN handled by the final
// min: at g=63, hi<=x implies x>=eN, and x>eN is excluded by the range check,
// so the +1 overshoot to 64 is exactly the x==eN case -> clamp to 63.
// Invalid (masked-out / out-of-range / NaN) -> row NB (trash).
// ---------------------------------------------------------------------------
#define BINV(x, mv, row)                                                     \
    {                                                                        \
        float t_ = ((x) - e0) * invstep;                                     \
        int g_ = (int)t_;                                                    \
        g_ = min(max(g_, 0), NB - 1);                                        \
        float lo_ = fmaf((float)g_, step, e0);        /* == edges[g] */      \
        float hi_ = fmaf((float)(g_ + 1), step, e0);  /* == edges[g+1] */    \
        g_ += (hi_ <= (x)) ? 1 : 0;                                          \
        g_ -= (lo_ > (x)) ? 1 : 0;                                           \
        g_ = min(g_, NB - 1);                                                \
        bool valid_ = (mv) && ((x) >= e0) && ((x) <= eN);                    \
        (row) = valid_ ? g_ : NB;                                            \
    }

// Fallback: exact binning against arbitrary sorted edges (LDS pairs, loops).
__device__ __forceinline__ int bin_lds(float x, const float2* __restrict__ ep,
                                       float e0, float eN, float invstep) {
    if (!(x >= e0) || !(x <= eN)) return -1;
    if (x == eN) return NB - 1;
    int g = (int)((x - e0) * invstep);
    g = min(max(g, 0), NB - 1);
    float2 p = ep[g];
    while (p.x > x) { --g; p = ep[g]; }
    while (p.y <= x) { ++g; p = ep[g]; }
    return g;
}

// ---------------------------------------------------------------------------
// Kernel 1: fused dual masked histogram.
// LDS layout: hist[arr][row][col], addr = ((arr*ROWS+row)<<5) + (lane&31)
// -> bank = lane&31 always: data-independent, conflict-free.
// Hot loop: branchless, 2-stage software pipeline PINNED with
// sched_barrier(0) so prefetch loads cannot sink into the compute.
// ---------------------------------------------------------------------------
template <bool AFFINE>
__device__ __forceinline__ void
stream_hist(const float4* __restrict__ o4, const float4* __restrict__ p4,
            const int4* __restrict__ m4, int startV, int endV, int tid,
            unsigned int* __restrict__ hobs, unsigned int* __restrict__ hpred,
            const float2* __restrict__ s_epair,
            float e0, float eN, float step, float invstep)
{
#define PROC(o, q, m)                                                        \
    do {                                                                     \
        int r0, r1, r2, r3, r4, r5, r6, r7;                                  \
        if (AFFINE) {                                                        \
            BINV((o).x, (m).x, r0); BINV((q).x, (m).x, r1);                  \
            BINV((o).y, (m).y, r2); BINV((q).y, (m).y, r3);                  \
            BINV((o).z, (m).z, r4); BINV((q).z, (m).z, r5);                  \
            BINV((o).w, (m).w, r6); BINV((q).w, (m).w, r7);                  \
        } else {                                                             \
            int t;                                                           \
            t = bin_lds((o).x, s_epair, e0, eN, invstep);                    \
            r0 = ((m).x && t >= 0) ? t : NB;                                 \
            t = bin_lds((q).x, s_epair, e0, eN, invstep);                    \
            r1 = ((m).x && t >= 0) ? t : NB;                                 \
            t = bin_lds((o).y, s_epair, e0, eN, invstep);                    \
            r2 = ((m).y && t >= 0) ? t : NB;                                 \
            t = bin_lds((q).y, s_epair, e0, eN, invstep);                    \
            r3 = ((m).y && t >= 0) ? t : NB;                                 \
            t = bin_lds((o).z, s_epair, e0, eN, invstep);                    \
            r4 = ((m).z && t >= 0) ? t : NB;                                 \
            t = bin_lds((q).z, s_epair, e0, eN, invstep);                    \
            r5 = ((m).z && t >= 0) ? t : NB;                                 \
            t = bin_lds((o).w, s_epair, e0, eN, invstep);                    \
            r6 = ((m).w && t >= 0) ? t : NB;                                 \
            t = bin_lds((q).w, s_epair, e0, eN, invstep);                    \
            r7 = ((m).w && t >= 0) ? t : NB;                                 \
        }                                                                    \
        atomicAdd(hobs  + (r0 << 5), 1u);                                    \
        atomicAdd(hpred + (r1 << 5), 1u);                                    \
        atomicAdd(hobs  + (r2 << 5), 1u);                                    \
        atomicAdd(hpred + (r3 << 5), 1u);                                    \
        atomicAdd(hobs  + (r4 << 5), 1u);                                    \
        atomicAdd(hpred + (r5 << 5), 1u);                                    \
        atomicAdd(hobs  + (r6 << 5), 1u);                                    \
        atomicAdd(hpred + (r7 << 5), 1u);                                    \
    } while (0)

    const int nFull = (endV - startV) / 512;   // full 2-triple stages
    int i = startV + tid;

    float4 oA, qA, oB, qB;
    int4   mA, mB;
    if (nFull > 0) {
        oA = o4[i];       qA = p4[i];       mA = m4[i];
        oB = o4[i + 256]; qB = p4[i + 256]; mB = m4[i + 256];
    }
    for (int s = 0; s < nFull; ++s) {
        // issue next stage's 6 loads; the fences below pin them HERE so the
        // compiler must keep their destinations live across the compute.
        const int j = (s + 1 < nFull) ? (i + 512) : (startV + tid);
        float4 oC = o4[j];       float4 qC = p4[j];       int4 mC = m4[j];
        float4 oD = o4[j + 256]; float4 qD = p4[j + 256]; int4 mD = m4[j + 256];
        __builtin_amdgcn_sched_barrier(0);
        PROC(oA, qA, mA);
        PROC(oB, qB, mB);
        __builtin_amdgcn_sched_barrier(0);
        oA = oC; qA = qC; mA = mC;
        oB = oD; qB = qD; mB = mD;
        i += 512;
    }
    // tail (generic; empty for the benchmark shape)
    for (; i < endV; i += 256) {
        float4 o = o4[i]; float4 q = p4[i]; int4 m = m4[i];
        PROC(o, q, m);
    }
#undef PROC
}

__global__ void __launch_bounds__(256)
hist_kernel(const float* __restrict__ obs,
            const float* __restrict__ pred,
            const int*   __restrict__ mask,
            const float* __restrict__ edges,
            unsigned int* __restrict__ counts,   // [2][B][NB]
            int elemsPerBatch, int blocksPerBatch, int B)
{
    __shared__ unsigned int s_hist[2][ROWS][RC];
    __shared__ float2       s_epair[NB];
    __shared__ int          s_affine;

    const int tid = threadIdx.x;
    for (int i = tid; i < 2 * ROWS * RC; i += 256)
        (&s_hist[0][0][0])[i] = 0u;
    if (tid < NB) s_epair[tid] = make_float2(edges[tid], edges[tid + 1]);
    if (tid == 0) s_affine = 1;
    __syncthreads();

    const float e0 = edges[0];
    const float eN = edges[NB];
    const float step    = (eN - e0) / (float)NB;
    const float invstep = 1.0f / step;

    // verify register-reconstruction is bitwise-faithful to the edge array
    if (tid < NE) {
        float recon = fmaf((float)tid, step, e0);
        if (!(recon == edges[tid]) || !(step > 0.0f)) atomicAnd(&s_affine, 0);
    }
    __syncthreads();
    const bool affine = (s_affine != 0);

    const int b     = blockIdx.x / blocksPerBatch;
    const int chunk = blockIdx.x % blocksPerBatch;
    const int perBlock = elemsPerBatch / blocksPerBatch;
    const size_t base  = (size_t)b * (size_t)elemsPerBatch;

    const float4* o4 = reinterpret_cast<const float4*>(obs  + base);
    const float4* p4 = reinterpret_cast<const float4*>(pred + base);
    const int4*   m4 = reinterpret_cast<const int4*>(mask + base);

    const int startV = (chunk * perBlock) >> 2;
    const int endV   = startV + (perBlock >> 2);

    const int c = tid & (RC - 1);
    unsigned int* hobs  = &s_hist[0][0][0] + c;
    unsigned int* hpred = &s_hist[1][0][0] + c;

    if (affine)
        stream_hist<true >(o4, p4, m4, startV, endV, tid, hobs, hpred,
                           s_epair, e0, eN, step, invstep);
    else
        stream_hist<false>(o4, p4, m4, startV, endV, tid, hobs, hpred,
                           s_epair, e0, eN, step, invstep);

    __syncthreads();

    if (tid < NB) {
        unsigned int so = 0u, sp = 0u;
        #pragma unroll
        for (int r = 0; r < RC; ++r) {
            int col = (tid + r) & (RC - 1);      // rotated -> conflict-free
            so += s_hist[0][tid][col];
            sp += s_hist[1][tid][col];
        }
        if (so) atomicAdd(&counts[(size_t)b * NB + tid], so);
        if (sp) atomicAdd(&counts[(size_t)B * NB + (size_t)b * NB + tid], sp);
    }
}

// ---------------------------------------------------------------------------
// Kernel 2: finalize. One wave, lane t = bin t.
// out[0] = w2_loss, out[1 .. 1+B*NB) = p_obs, out[1+B*NB ..) = p_pred
// ---------------------------------------------------------------------------
__device__ __forceinline__ float wave_sum64(float v) {
    for (int o = 32; o > 0; o >>= 1) v += __shfl_xor(v, o, 64);
    return v;
}
__device__ __forceinline__ float wave_incl_scan64(float v, int lane) {
    for (int d = 1; d < 64; d <<= 1) {
        float u = __shfl_up(v, d, 64);
        if (lane >= d) v += u;
    }
    return v;
}

__global__ void __launch_bounds__(64)
finalize_kernel(const unsigned int* __restrict__ counts,
                const float* __restrict__ edges,
                const float* __restrict__ bweights,
                float* __restrict__ out, int B)
{
    const int t = threadIdx.x;    // 0..63 == bin index

    float midA = 0.5f * (edges[t] + edges[t + 1]);
    float width;
    if (t < NB - 1) {
        float midB = 0.5f * (edges[t + 1] + edges[t + 2]);
        width = midB - midA;
    } else {
        float midPrev = 0.5f * (edges[NB - 2] + edges[NB - 1]);
        width = midA - midPrev;
    }
    const float bw = bweights[t];

    float loss_acc = 0.0f;
    for (int b = 0; b < B; ++b) {
        float co = (float)counts[(size_t)b * NB + t];
        float cp = (float)counts[(size_t)B * NB + (size_t)b * NB + t];

        float to = wave_sum64(co);
        if (to == 0.0f) { co = 1.0f; to = 64.0f; }
        float tp = wave_sum64(cp);
        if (tp == 0.0f) { cp = 1.0f; tp = 64.0f; }

        float po = co / to;
        float pp = cp / tp;
        out[1 + (size_t)b * NB + t]                  = po;
        out[1 + (size_t)B * NB + (size_t)b * NB + t] = pp;

        float cdfo = wave_incl_scan64(po, t);
        float cdfp = wave_incl_scan64(pp, t);
        float d = cdfo - cdfp;
        float wd = d * d * width * bw;
        float s = wave_sum64(wd);
        if (t == 0) loss_acc += s;
    }
    if (t == 0) out[0] = loss_acc / (float)B;
}

// ---------------------------------------------------------------------------
extern "C" void kernel_launch(void* const* d_in, const int* in_sizes, int n_in,
                              void* d_out, int out_size, void* d_ws, size_t ws_size,
                              hipStream_t stream) {
    const float* obs      = (const float*)d_in[0];
    const float* pred     = (const float*)d_in[1];
    const int*   mask     = (const int*)d_in[2];
    const float* edges    = (const float*)d_in[3];
    const float* bweights = (const float*)d_in[4];
    float* out = (float*)d_out;

    const int nb = in_sizes[3] - 1;                 // 64
    const int B  = (out_size - 1) / (2 * nb);       // 32
    const int elemsPerBatch = in_sizes[0] / B;      // 1048576

    unsigned int* counts = (unsigned int*)d_ws;     // [2][B][nb] uint32
    const size_t countsBytes = (size_t)2 * B * nb * sizeof(unsigned int);

    hipMemsetAsync(d_ws, 0, countsBytes, stream);

    const int blocksPerBatch = 64;                  // 16384 elems / block
    dim3 grid(B * blocksPerBatch), block(256);
    hist_kernel<<<grid, block, 0, stream>>>(obs, pred, mask, edges, counts,
                                            elemsPerBatch, blocksPerBatch, B);

    finalize_kernel<<<1, 64, 0, stream>>>(counts, edges, bweights, out, B);
}